// Round 1
// baseline (562.306 us; speedup 1.0000x reference)
//
#include <hip/hip_runtime.h>

// ---------------- problem constants ----------------
#define DD    128   // channel dim
#define LINE  256   // attention-axis length (H == W == 256)
#define TILE  64    // interior positions per block (256 = 4 segs, exact)
#define NROW  66    // staged kv rows: TILE + 2 halo
#define NROWP 80    // padded row count for 5 MFMA row-tiles of 16
#define LSTR  136   // LDS row stride in bf16 elements (272 B, 16B-aligned rows)

typedef __bf16 bf16x8 __attribute__((ext_vector_type(8)));
typedef float  f32x4v __attribute__((ext_vector_type(4)));
typedef float  f32x2v __attribute__((ext_vector_type(2)));
typedef unsigned int u32x2v __attribute__((ext_vector_type(2)));
typedef unsigned int u32x4v __attribute__((ext_vector_type(4)));

static __device__ __forceinline__ unsigned short f2bf(float f) {
  union { float f; unsigned u; } v; v.f = f;
  unsigned u = v.u + 0x7FFFu + ((v.u >> 16) & 1u);   // RNE
  return (unsigned short)(u >> 16);
}
#define BF_LO(u) __uint_as_float((u) << 16)
#define BF_HI(u) __uint_as_float((u) & 0xffff0000u)

// ---------------- M = (Wq^T @ Wk) / sqrt(D), bf16, one per axis --------------
__global__ void make_m_kernel(const float* __restrict__ Wq_h, const float* __restrict__ Wk_h,
                              const float* __restrict__ Wq_w, const float* __restrict__ Wk_w,
                              unsigned short* __restrict__ Ms) {
  const float* Wq = blockIdx.y ? Wq_w : Wq_h;
  const float* Wk = blockIdx.y ? Wk_w : Wk_h;
  unsigned short* M = Ms + blockIdx.y * (DD * DD);
  int d = blockIdx.x, c = threadIdx.x;
  float acc = 0.f;
  for (int e = 0; e < DD; ++e) acc += Wq[e * DD + d] * Wk[e * DD + c];
  M[d * DD + c] = f2bf(acc * 0.08838834764831845f);  // 1/sqrt(128)
}

// ---------------- fused band attention along one axis ----------------
// AXIS==0: lines are (b,w), positions along h (stride W*D)
// AXIS==1: lines are (b,h), positions along w (stride D)
template <int AXIS, bool ADD>
__global__ __launch_bounds__(256) void axial_pass(const float* __restrict__ x,
                                                  const float* __restrict__ kv,
                                                  const unsigned short* __restrict__ M,
                                                  float* __restrict__ out) {
  __shared__ unsigned short kv_s[NROWP * LSTR];   // bf16, rows 0..65 staged, 66..79 zero
  __shared__ unsigned short x_s[TILE * LSTR];     // bf16
  __shared__ unsigned short kvm_s[NROW * LSTR];   // bf16, M @ kv per staged row
  __shared__ float s_s[3 * TILE];
  __shared__ float p_s[3 * TILE];

  const int tid  = threadIdx.x;
  const int seg0 = blockIdx.x * TILE;   // global position of interior row 0
  const int line = blockIdx.y;

  size_t base; int stride;
  if (AXIS == 0) {
    int b = line >> 8, w = line & 255;
    base = (size_t)b * (256 * 256 * 128) + (size_t)w * DD;
    stride = 256 * 128;
  } else {
    base = (size_t)line * (256 * 128);
    stride = DD;
  }

  // ---- stage kv rows 0..65 = positions seg0-1 .. seg0+64 (clamped at line ends)
  for (int u = tid; u < NROWP * 32; u += 256) {
    int row = u >> 5, c4 = u & 31;
    u32x2v wv; wv.x = 0u; wv.y = 0u;
    if (row < NROW) {
      int pos = seg0 - 1 + row;
      pos = pos < 0 ? 0 : (pos > LINE - 1 ? LINE - 1 : pos);
      f32x4v v = *(const f32x4v*)(kv + base + (size_t)pos * stride + c4 * 4);
      wv.x = (unsigned)f2bf(v.x) | ((unsigned)f2bf(v.y) << 16);
      wv.y = (unsigned)f2bf(v.z) | ((unsigned)f2bf(v.w) << 16);
    }
    *(u32x2v*)&kv_s[row * LSTR + c4 * 4] = wv;
  }
  // ---- stage x rows 0..63 = positions seg0 .. seg0+63
  for (int u = tid; u < TILE * 32; u += 256) {
    int row = u >> 5, c4 = u & 31;
    f32x4v v = *(const f32x4v*)(x + base + (size_t)(seg0 + row) * stride + c4 * 4);
    u32x2v wv;
    wv.x = (unsigned)f2bf(v.x) | ((unsigned)f2bf(v.y) << 16);
    wv.y = (unsigned)f2bf(v.z) | ((unsigned)f2bf(v.w) << 16);
    *(u32x2v*)&x_s[row * LSTR + c4 * 4] = wv;
  }
  __syncthreads();

  // ---- kvm[i][d] = sum_c kv[i][c] * M[d][c]  via mfma_f32_16x16x32_bf16
  // Waves split by column-tile pair so M is fetched once per block.
  {
    const int wave = tid >> 6, lane = tid & 63;
    const int r16 = lane & 15, q = lane >> 4;
    for (int ct = wave * 2; ct < wave * 2 + 2; ++ct) {
      bf16x8 b[4];
#pragma unroll
      for (int ks = 0; ks < 4; ++ks)
        b[ks] = __builtin_bit_cast(
            bf16x8, *(const u32x4v*)(M + (ct * 16 + r16) * DD + ks * 32 + q * 8));
#pragma unroll
      for (int rt = 0; rt < 5; ++rt) {
        f32x4v acc = {0.f, 0.f, 0.f, 0.f};
#pragma unroll
        for (int ks = 0; ks < 4; ++ks) {
          bf16x8 a = __builtin_bit_cast(
              bf16x8, *(const u32x4v*)&kv_s[(rt * 16 + r16) * LSTR + ks * 32 + q * 8]);
          acc = __builtin_amdgcn_mfma_f32_16x16x32_bf16(a, b[ks], acc, 0, 0, 0);
        }
        int col = ct * 16 + r16;
#pragma unroll
        for (int r = 0; r < 4; ++r) {
          int row = rt * 16 + q * 4 + r;   // D row = quad*4 + reg  (m89/m91 layout)
          if (row < NROW) kvm_s[row * LSTR + col] = f2bf(acc[r]);
        }
      }
    }
  }
  __syncthreads();

  // ---- band dots: s_off(i) = x[i] . kvm[i+off], off in {0,1,2} (j = gp-1+off)
  {
    int i = tid >> 2, sub = tid & 3;        // 4 threads share one position
    float s0 = 0.f, s1 = 0.f, s2 = 0.f;
#pragma unroll
    for (int ch = 0; ch < 4; ++ch) {
      int off = sub * 32 + ch * 8;
      float xf[8];
      {
        u32x4v t = *(const u32x4v*)&x_s[i * LSTR + off];
        xf[0] = BF_LO(t.x); xf[1] = BF_HI(t.x); xf[2] = BF_LO(t.y); xf[3] = BF_HI(t.y);
        xf[4] = BF_LO(t.z); xf[5] = BF_HI(t.z); xf[6] = BF_LO(t.w); xf[7] = BF_HI(t.w);
      }
      {
        u32x4v t = *(const u32x4v*)&kvm_s[(i + 0) * LSTR + off];
        s0 += xf[0]*BF_LO(t.x) + xf[1]*BF_HI(t.x) + xf[2]*BF_LO(t.y) + xf[3]*BF_HI(t.y)
            + xf[4]*BF_LO(t.z) + xf[5]*BF_HI(t.z) + xf[6]*BF_LO(t.w) + xf[7]*BF_HI(t.w);
      }
      {
        u32x4v t = *(const u32x4v*)&kvm_s[(i + 1) * LSTR + off];
        s1 += xf[0]*BF_LO(t.x) + xf[1]*BF_HI(t.x) + xf[2]*BF_LO(t.y) + xf[3]*BF_HI(t.y)
            + xf[4]*BF_LO(t.z) + xf[5]*BF_HI(t.z) + xf[6]*BF_LO(t.w) + xf[7]*BF_HI(t.w);
      }
      {
        u32x4v t = *(const u32x4v*)&kvm_s[(i + 2) * LSTR + off];
        s2 += xf[0]*BF_LO(t.x) + xf[1]*BF_HI(t.x) + xf[2]*BF_LO(t.y) + xf[3]*BF_HI(t.y)
            + xf[4]*BF_LO(t.z) + xf[5]*BF_HI(t.z) + xf[6]*BF_LO(t.w) + xf[7]*BF_HI(t.w);
      }
    }
    s0 += __shfl_xor(s0, 1); s0 += __shfl_xor(s0, 2);
    s1 += __shfl_xor(s1, 1); s1 += __shfl_xor(s1, 2);
    s2 += __shfl_xor(s2, 1); s2 += __shfl_xor(s2, 2);
    if (sub == 0) {
      int gp = seg0 + i;
      s_s[0 * TILE + i] = (gp - 1 >= 0)   ? s0 : -1e30f;
      s_s[1 * TILE + i] = s1;
      s_s[2 * TILE + i] = (gp + 1 < LINE) ? s2 : -1e30f;
    }
  }
  __syncthreads();

  // ---- 3-entry softmax (masked entries underflow to exactly 0, matching ref)
  if (tid < TILE) {
    float s0 = s_s[0 * TILE + tid], s1 = s_s[1 * TILE + tid], s2 = s_s[2 * TILE + tid];
    float m = fmaxf(s0, fmaxf(s1, s2));
    float e0 = __expf(s0 - m), e1 = __expf(s1 - m), e2 = __expf(s2 - m);
    float inv = 1.f / (e0 + e1 + e2);
    p_s[0 * TILE + tid] = e0 * inv;
    p_s[1 * TILE + tid] = e1 * inv;
    p_s[2 * TILE + tid] = e2 * inv;
  }
  __syncthreads();

  // ---- out[i][d] = sum_off p[off][i] * kv[i+off][d]  (raw kv values, per ref)
  for (int r = 0; r < 16; ++r) {
    int u  = r * 256 + tid;
    int i  = u >> 6, dp = u & 63;         // lanes: consecutive dp -> coalesced stores
    float p0 = p_s[0 * TILE + i], p1 = p_s[1 * TILE + i], p2 = p_s[2 * TILE + i];
    unsigned a0 = *(const unsigned*)&kv_s[(i + 0) * LSTR + dp * 2];
    unsigned a1 = *(const unsigned*)&kv_s[(i + 1) * LSTR + dp * 2];
    unsigned a2 = *(const unsigned*)&kv_s[(i + 2) * LSTR + dp * 2];
    f32x2v o;
    o.x = p0 * BF_LO(a0) + p1 * BF_LO(a1) + p2 * BF_LO(a2);
    o.y = p0 * BF_HI(a0) + p1 * BF_HI(a1) + p2 * BF_HI(a2);
    size_t oidx = base + (size_t)(seg0 + i) * stride + dp * 2;
    if (ADD) {
      f32x2v prev = *(const f32x2v*)(out + oidx);
      o.x += prev.x; o.y += prev.y;
    }
    *(f32x2v*)(out + oidx) = o;
  }
}

extern "C" void kernel_launch(void* const* d_in, const int* in_sizes, int n_in,
                              void* d_out, int out_size, void* d_ws, size_t ws_size,
                              hipStream_t stream) {
  const float* x    = (const float*)d_in[0];
  const float* kv   = (const float*)d_in[1];
  const float* Wq_h = (const float*)d_in[2];
  const float* Wk_h = (const float*)d_in[3];
  const float* Wq_w = (const float*)d_in[4];
  const float* Wk_w = (const float*)d_in[5];
  float* out = (float*)d_out;
  unsigned short* Ms = (unsigned short*)d_ws;  // 2 x 128x128 bf16 = 64 KB scratch

  make_m_kernel<<<dim3(DD, 2), dim3(DD), 0, stream>>>(Wq_h, Wk_h, Wq_w, Wk_w, Ms);

  dim3 grid(LINE / TILE, 4 * 256);  // 4 segments x (B*256) lines
  axial_pass<0, false><<<grid, dim3(256), 0, stream>>>(x, kv, Ms, out);            // h-axis
  axial_pass<1, true ><<<grid, dim3(256), 0, stream>>>(x, kv, Ms + DD * DD, out);  // w-axis (+=)
}

// Round 2
// 437.054 us; speedup vs baseline: 1.2866x; 1.2866x over previous
//
#include <hip/hip_runtime.h>

// ---------------- problem constants ----------------
#define DD    128   // channel dim
#define LINE  256   // attention-axis length (H == W == 256)
#define NPOS  262144  // B*H*W = 4*256*256
#define TILE  64    // (fallback path) interior positions per block
#define NROW  66
#define NROWP 80
#define LSTR  136   // LDS row stride in bf16 elements (272 B, 16B-aligned rows)

typedef __bf16 bf16x8 __attribute__((ext_vector_type(8)));
typedef float  f32x4v __attribute__((ext_vector_type(4)));
typedef float  f32x2v __attribute__((ext_vector_type(2)));
typedef unsigned int u32x2v __attribute__((ext_vector_type(2)));
typedef unsigned int u32x4v __attribute__((ext_vector_type(4)));

static __device__ __forceinline__ unsigned short f2bf(float f) {
  union { float f; unsigned u; } v; v.f = f;
  unsigned u = v.u + 0x7FFFu + ((v.u >> 16) & 1u);   // RNE
  return (unsigned short)(u >> 16);
}
#define BF_LO(u) __uint_as_float((u) << 16)
#define BF_HI(u) __uint_as_float((u) & 0xffff0000u)

// =====================================================================
// NEW PATH (3 kernels, barrier-free band kernel)
// =====================================================================

// Mt[axis][d][c] = sum_e Wq[e][c] * Wk[e][d] / sqrt(D)
// (B-fragment layout for XM = X @ M: row = output col d, contiguous = k = c)
__global__ void make_mt_kernel(const float* __restrict__ Wq_h, const float* __restrict__ Wk_h,
                               const float* __restrict__ Wq_w, const float* __restrict__ Wk_w,
                               unsigned short* __restrict__ Ms) {
  const float* Wq = blockIdx.y ? Wq_w : Wq_h;
  const float* Wk = blockIdx.y ? Wk_w : Wk_h;
  unsigned short* M = Ms + blockIdx.y * (DD * DD);
  int d = blockIdx.x, c = threadIdx.x;
  float acc = 0.f;
  for (int e = 0; e < DD; ++e) acc += Wq[e * DD + c] * Wk[e * DD + d];  // Wk uniform -> scalar
  M[d * DD + c] = f2bf(acc * 0.08838834764831845f);  // 1/sqrt(128)
}

// XM_{h,w}[i][d] = sum_c x[i][c] * Mt[{h,w}][d][c]   (bf16 out)
// 64 rows/block; 4 waves: wave>>1 picks matrix, wave&1 picks column half.
__global__ __launch_bounds__(256) void project_kernel(const float* __restrict__ x,
                                                      const unsigned short* __restrict__ Mt,
                                                      unsigned short* __restrict__ XMh,
                                                      unsigned short* __restrict__ XMw) {
  __shared__ unsigned short x_s[64 * LSTR];
  const int tid = threadIdx.x;
  const long row0 = (long)blockIdx.x * 64;

  for (int u = tid; u < 64 * 32; u += 256) {
    int row = u >> 5, c4 = u & 31;
    f32x4v v = *(const f32x4v*)(x + (row0 + row) * DD + c4 * 4);
    u32x2v wv;
    wv.x = (unsigned)f2bf(v.x) | ((unsigned)f2bf(v.y) << 16);
    wv.y = (unsigned)f2bf(v.z) | ((unsigned)f2bf(v.w) << 16);
    *(u32x2v*)&x_s[row * LSTR + c4 * 4] = wv;
  }
  __syncthreads();

  const int wave = tid >> 6, lane = tid & 63;
  const int r16 = lane & 15, q = lane >> 4;
  const unsigned short* Mm = Mt + (wave >> 1) * (DD * DD);
  unsigned short* XO = (wave >> 1) ? XMw : XMh;

#pragma unroll
  for (int ci = 0; ci < 4; ++ci) {
    int ct = (wave & 1) * 4 + ci;
    bf16x8 b[4];
#pragma unroll
    for (int ks = 0; ks < 4; ++ks)
      b[ks] = __builtin_bit_cast(
          bf16x8, *(const u32x4v*)(Mm + (ct * 16 + r16) * DD + ks * 32 + q * 8));
#pragma unroll
    for (int rt = 0; rt < 4; ++rt) {
      f32x4v acc = {0.f, 0.f, 0.f, 0.f};
#pragma unroll
      for (int ks = 0; ks < 4; ++ks) {
        bf16x8 a = __builtin_bit_cast(
            bf16x8, *(const u32x4v*)&x_s[(rt * 16 + r16) * LSTR + ks * 32 + q * 8]);
        acc = __builtin_amdgcn_mfma_f32_16x16x32_bf16(a, b[ks], acc, 0, 0, 0);
      }
#pragma unroll
      for (int r = 0; r < 4; ++r) {
        long row = row0 + rt * 16 + q * 4 + r;   // C/D: col=lane&15, row=quad*4+reg
        XO[row * DD + ct * 16 + r16] = f2bf(acc[r]);
      }
    }
  }
}

static __device__ __forceinline__ float dot8(const float q[8], f32x4v a, f32x4v b) {
  return q[0] * a.x + q[1] * a.y + q[2] * a.z + q[3] * a.w
       + q[4] * b.x + q[5] * b.y + q[6] * b.z + q[7] * b.w;
}
static __device__ __forceinline__ float red16(float v) {
#pragma unroll
  for (int m = 1; m < 16; m <<= 1) v += __shfl_xor(v, m, 16);
  return v;
}
static __device__ __forceinline__ void dec4(unsigned lo, unsigned hi, float* q) {
  q[0] = BF_LO(lo); q[1] = BF_HI(lo); q[2] = BF_LO(hi); q[3] = BF_HI(hi);
}

// Fused both-axes band attention. 16 lanes per position; no LDS, no barriers.
__global__ __launch_bounds__(256) void band_kernel(const float* __restrict__ kv,
                                                   const unsigned short* __restrict__ XMh,
                                                   const unsigned short* __restrict__ XMw,
                                                   float* __restrict__ out) {
  const int tid = threadIdx.x;
  const int g = tid >> 4, l = tid & 15;
  const int w = blockIdx.x * 16 + g;
  const int y = blockIdx.y;               // b*256 + h
  const int h = y & 255;
  const long pos = (long)y * 256 + w;     // row index into kv/out/XM
  const long pn = (h > 0)    ? pos - 256 : pos;
  const long ps = (h < 255)  ? pos + 256 : pos;
  const long pw = (w > 0)    ? pos - 1   : pos;
  const long pe = (w < 255)  ? pos + 1   : pos;
  const int c0 = l * 4, c1 = 64 + l * 4;  // two contiguous 256B spans per 16-lane group

  f32x4v cA = *(const f32x4v*)(kv + pos * DD + c0);
  f32x4v cB = *(const f32x4v*)(kv + pos * DD + c1);
  f32x4v nA = *(const f32x4v*)(kv + pn * DD + c0);
  f32x4v nB = *(const f32x4v*)(kv + pn * DD + c1);
  f32x4v sA = *(const f32x4v*)(kv + ps * DD + c0);
  f32x4v sB = *(const f32x4v*)(kv + ps * DD + c1);
  f32x4v wA = *(const f32x4v*)(kv + pw * DD + c0);
  f32x4v wB = *(const f32x4v*)(kv + pw * DD + c1);
  f32x4v eA = *(const f32x4v*)(kv + pe * DD + c0);
  f32x4v eB = *(const f32x4v*)(kv + pe * DD + c1);

  u32x2v xh0 = *(const u32x2v*)(XMh + pos * DD + c0);
  u32x2v xh1 = *(const u32x2v*)(XMh + pos * DD + c1);
  u32x2v xw0 = *(const u32x2v*)(XMw + pos * DD + c0);
  u32x2v xw1 = *(const u32x2v*)(XMw + pos * DD + c1);
  float qh[8], qw[8];
  dec4(xh0.x, xh0.y, qh); dec4(xh1.x, xh1.y, qh + 4);
  dec4(xw0.x, xw0.y, qw); dec4(xw1.x, xw1.y, qw + 4);

  float sh_n = red16(dot8(qh, nA, nB));
  float sh_c = red16(dot8(qh, cA, cB));
  float sh_s = red16(dot8(qh, sA, sB));
  float sw_w = red16(dot8(qw, wA, wB));
  float sw_c = red16(dot8(qw, cA, cB));
  float sw_e = red16(dot8(qw, eA, eB));

  if (h == 0)   sh_n = -1e30f;
  if (h == 255) sh_s = -1e30f;
  if (w == 0)   sw_w = -1e30f;
  if (w == 255) sw_e = -1e30f;

  float mh = fmaxf(sh_n, fmaxf(sh_c, sh_s));
  float e0 = __expf(sh_n - mh), e1 = __expf(sh_c - mh), e2 = __expf(sh_s - mh);
  float ih = 1.f / (e0 + e1 + e2);
  float ph0 = e0 * ih, ph1 = e1 * ih, ph2 = e2 * ih;

  float mw = fmaxf(sw_w, fmaxf(sw_c, sw_e));
  float f0 = __expf(sw_w - mw), f1 = __expf(sw_c - mw), f2 = __expf(sw_e - mw);
  float iw = 1.f / (f0 + f1 + f2);
  float pw0 = f0 * iw, pw1 = f1 * iw, pw2 = f2 * iw;

  float pc = ph1 + pw1;
  f32x4v oA, oB;
  oA.x = ph0 * nA.x + pc * cA.x + ph2 * sA.x + pw0 * wA.x + pw2 * eA.x;
  oA.y = ph0 * nA.y + pc * cA.y + ph2 * sA.y + pw0 * wA.y + pw2 * eA.y;
  oA.z = ph0 * nA.z + pc * cA.z + ph2 * sA.z + pw0 * wA.z + pw2 * eA.z;
  oA.w = ph0 * nA.w + pc * cA.w + ph2 * sA.w + pw0 * wA.w + pw2 * eA.w;
  oB.x = ph0 * nB.x + pc * cB.x + ph2 * sB.x + pw0 * wB.x + pw2 * eB.x;
  oB.y = ph0 * nB.y + pc * cB.y + ph2 * sB.y + pw0 * wB.y + pw2 * eB.y;
  oB.z = ph0 * nB.z + pc * cB.z + ph2 * sB.z + pw0 * wB.z + pw2 * eB.z;
  oB.w = ph0 * nB.w + pc * cB.w + ph2 * sB.w + pw0 * wB.w + pw2 * eB.w;
  *(f32x4v*)(out + pos * DD + c0) = oA;
  *(f32x4v*)(out + pos * DD + c1) = oB;
}

// =====================================================================
// FALLBACK PATH (Round-1, validated) — used only if ws_size is too small
// =====================================================================
__global__ void make_m_kernel(const float* __restrict__ Wq_h, const float* __restrict__ Wk_h,
                              const float* __restrict__ Wq_w, const float* __restrict__ Wk_w,
                              unsigned short* __restrict__ Ms) {
  const float* Wq = blockIdx.y ? Wq_w : Wq_h;
  const float* Wk = blockIdx.y ? Wk_w : Wk_h;
  unsigned short* M = Ms + blockIdx.y * (DD * DD);
  int d = blockIdx.x, c = threadIdx.x;
  float acc = 0.f;
  for (int e = 0; e < DD; ++e) acc += Wq[e * DD + d] * Wk[e * DD + c];
  M[d * DD + c] = f2bf(acc * 0.08838834764831845f);
}

template <int AXIS, bool ADD>
__global__ __launch_bounds__(256) void axial_pass(const float* __restrict__ x,
                                                  const float* __restrict__ kv,
                                                  const unsigned short* __restrict__ M,
                                                  float* __restrict__ out) {
  __shared__ unsigned short kv_s[NROWP * LSTR];
  __shared__ unsigned short x_s[TILE * LSTR];
  __shared__ unsigned short kvm_s[NROW * LSTR];
  __shared__ float s_s[3 * TILE];
  __shared__ float p_s[3 * TILE];

  const int tid  = threadIdx.x;
  const int seg0 = blockIdx.x * TILE;
  const int line = blockIdx.y;

  size_t base; int stride;
  if (AXIS == 0) {
    int b = line >> 8, w = line & 255;
    base = (size_t)b * (256 * 256 * 128) + (size_t)w * DD;
    stride = 256 * 128;
  } else {
    base = (size_t)line * (256 * 128);
    stride = DD;
  }

  for (int u = tid; u < NROWP * 32; u += 256) {
    int row = u >> 5, c4 = u & 31;
    u32x2v wv; wv.x = 0u; wv.y = 0u;
    if (row < NROW) {
      int pos = seg0 - 1 + row;
      pos = pos < 0 ? 0 : (pos > LINE - 1 ? LINE - 1 : pos);
      f32x4v v = *(const f32x4v*)(kv + base + (size_t)pos * stride + c4 * 4);
      wv.x = (unsigned)f2bf(v.x) | ((unsigned)f2bf(v.y) << 16);
      wv.y = (unsigned)f2bf(v.z) | ((unsigned)f2bf(v.w) << 16);
    }
    *(u32x2v*)&kv_s[row * LSTR + c4 * 4] = wv;
  }
  for (int u = tid; u < TILE * 32; u += 256) {
    int row = u >> 5, c4 = u & 31;
    f32x4v v = *(const f32x4v*)(x + base + (size_t)(seg0 + row) * stride + c4 * 4);
    u32x2v wv;
    wv.x = (unsigned)f2bf(v.x) | ((unsigned)f2bf(v.y) << 16);
    wv.y = (unsigned)f2bf(v.z) | ((unsigned)f2bf(v.w) << 16);
    *(u32x2v*)&x_s[row * LSTR + c4 * 4] = wv;
  }
  __syncthreads();

  {
    const int wave = tid >> 6, lane = tid & 63;
    const int r16 = lane & 15, q = lane >> 4;
    for (int ct = wave * 2; ct < wave * 2 + 2; ++ct) {
      bf16x8 b[4];
#pragma unroll
      for (int ks = 0; ks < 4; ++ks)
        b[ks] = __builtin_bit_cast(
            bf16x8, *(const u32x4v*)(M + (ct * 16 + r16) * DD + ks * 32 + q * 8));
#pragma unroll
      for (int rt = 0; rt < 5; ++rt) {
        f32x4v acc = {0.f, 0.f, 0.f, 0.f};
#pragma unroll
        for (int ks = 0; ks < 4; ++ks) {
          bf16x8 a = __builtin_bit_cast(
              bf16x8, *(const u32x4v*)&kv_s[(rt * 16 + r16) * LSTR + ks * 32 + q * 8]);
          acc = __builtin_amdgcn_mfma_f32_16x16x32_bf16(a, b[ks], acc, 0, 0, 0);
        }
        int col = ct * 16 + r16;
#pragma unroll
        for (int r = 0; r < 4; ++r) {
          int row = rt * 16 + q * 4 + r;
          if (row < NROW) kvm_s[row * LSTR + col] = f2bf(acc[r]);
        }
      }
    }
  }
  __syncthreads();

  {
    int i = tid >> 2, sub = tid & 3;
    float s0 = 0.f, s1 = 0.f, s2 = 0.f;
#pragma unroll
    for (int ch = 0; ch < 4; ++ch) {
      int off = sub * 32 + ch * 8;
      float xf[8];
      {
        u32x4v t = *(const u32x4v*)&x_s[i * LSTR + off];
        xf[0] = BF_LO(t.x); xf[1] = BF_HI(t.x); xf[2] = BF_LO(t.y); xf[3] = BF_HI(t.y);
        xf[4] = BF_LO(t.z); xf[5] = BF_HI(t.z); xf[6] = BF_LO(t.w); xf[7] = BF_HI(t.w);
      }
      {
        u32x4v t = *(const u32x4v*)&kvm_s[(i + 0) * LSTR + off];
        s0 += xf[0]*BF_LO(t.x) + xf[1]*BF_HI(t.x) + xf[2]*BF_LO(t.y) + xf[3]*BF_HI(t.y)
            + xf[4]*BF_LO(t.z) + xf[5]*BF_HI(t.z) + xf[6]*BF_LO(t.w) + xf[7]*BF_HI(t.w);
      }
      {
        u32x4v t = *(const u32x4v*)&kvm_s[(i + 1) * LSTR + off];
        s1 += xf[0]*BF_LO(t.x) + xf[1]*BF_HI(t.x) + xf[2]*BF_LO(t.y) + xf[3]*BF_HI(t.y)
            + xf[4]*BF_LO(t.z) + xf[5]*BF_HI(t.z) + xf[6]*BF_LO(t.w) + xf[7]*BF_HI(t.w);
      }
      {
        u32x4v t = *(const u32x4v*)&kvm_s[(i + 2) * LSTR + off];
        s2 += xf[0]*BF_LO(t.x) + xf[1]*BF_HI(t.x) + xf[2]*BF_LO(t.y) + xf[3]*BF_HI(t.y)
            + xf[4]*BF_LO(t.z) + xf[5]*BF_HI(t.z) + xf[6]*BF_LO(t.w) + xf[7]*BF_HI(t.w);
      }
    }
    s0 += __shfl_xor(s0, 1); s0 += __shfl_xor(s0, 2);
    s1 += __shfl_xor(s1, 1); s1 += __shfl_xor(s1, 2);
    s2 += __shfl_xor(s2, 1); s2 += __shfl_xor(s2, 2);
    if (sub == 0) {
      int gp = seg0 + i;
      s_s[0 * TILE + i] = (gp - 1 >= 0)   ? s0 : -1e30f;
      s_s[1 * TILE + i] = s1;
      s_s[2 * TILE + i] = (gp + 1 < LINE) ? s2 : -1e30f;
    }
  }
  __syncthreads();

  if (tid < TILE) {
    float s0 = s_s[0 * TILE + tid], s1 = s_s[1 * TILE + tid], s2 = s_s[2 * TILE + tid];
    float m = fmaxf(s0, fmaxf(s1, s2));
    float e0 = __expf(s0 - m), e1 = __expf(s1 - m), e2 = __expf(s2 - m);
    float inv = 1.f / (e0 + e1 + e2);
    p_s[0 * TILE + tid] = e0 * inv;
    p_s[1 * TILE + tid] = e1 * inv;
    p_s[2 * TILE + tid] = e2 * inv;
  }
  __syncthreads();

  for (int r = 0; r < 16; ++r) {
    int u  = r * 256 + tid;
    int i  = u >> 6, dp = u & 63;
    float p0 = p_s[0 * TILE + i], p1 = p_s[1 * TILE + i], p2 = p_s[2 * TILE + i];
    unsigned a0 = *(const unsigned*)&kv_s[(i + 0) * LSTR + dp * 2];
    unsigned a1 = *(const unsigned*)&kv_s[(i + 1) * LSTR + dp * 2];
    unsigned a2 = *(const unsigned*)&kv_s[(i + 2) * LSTR + dp * 2];
    f32x2v o;
    o.x = p0 * BF_LO(a0) + p1 * BF_LO(a1) + p2 * BF_LO(a2);
    o.y = p0 * BF_HI(a0) + p1 * BF_HI(a1) + p2 * BF_HI(a2);
    size_t oidx = base + (size_t)(seg0 + i) * stride + dp * 2;
    if (ADD) {
      f32x2v prev = *(const f32x2v*)(out + oidx);
      o.x += prev.x; o.y += prev.y;
    }
    *(f32x2v*)(out + oidx) = o;
  }
}

// =====================================================================
extern "C" void kernel_launch(void* const* d_in, const int* in_sizes, int n_in,
                              void* d_out, int out_size, void* d_ws, size_t ws_size,
                              hipStream_t stream) {
  const float* x    = (const float*)d_in[0];
  const float* kv   = (const float*)d_in[1];
  const float* Wq_h = (const float*)d_in[2];
  const float* Wk_h = (const float*)d_in[3];
  const float* Wq_w = (const float*)d_in[4];
  const float* Wk_w = (const float*)d_in[5];
  float* out = (float*)d_out;

  const size_t ms_bytes = 2ull * DD * DD * 2;                  // 65536
  const size_t xm_bytes = (size_t)NPOS * DD * 2;               // 67108864 each
  const size_t need = ms_bytes + 2 * xm_bytes;                 // 134283264

  if (ws_size >= need) {
    unsigned short* Ms  = (unsigned short*)d_ws;
    unsigned short* XMh = (unsigned short*)((char*)d_ws + ms_bytes);
    unsigned short* XMw = XMh + (size_t)NPOS * DD;

    make_mt_kernel<<<dim3(DD, 2), dim3(DD), 0, stream>>>(Wq_h, Wk_h, Wq_w, Wk_w, Ms);
    project_kernel<<<dim3(NPOS / 64), dim3(256), 0, stream>>>(x, Ms, XMh, XMw);
    band_kernel<<<dim3(LINE / 16, 4 * LINE), dim3(256), 0, stream>>>(kv, XMh, XMw, out);
  } else {
    unsigned short* Ms = (unsigned short*)d_ws;  // 64 KB
    make_m_kernel<<<dim3(DD, 2), dim3(DD), 0, stream>>>(Wq_h, Wk_h, Wq_w, Wk_w, Ms);
    dim3 grid(LINE / TILE, 4 * 256);
    axial_pass<0, false><<<grid, dim3(256), 0, stream>>>(x, kv, Ms, out);
    axial_pass<1, true ><<<grid, dim3(256), 0, stream>>>(x, kv, Ms + DD * DD, out);
  }
}